// Round 16
// baseline (213.352 us; speedup 1.0000x reference)
//
#include <hip/hip_runtime.h>
#include <stdint.h>

#define NODES 8192
#define DIM   128
#define NLAYERS 3
#define SK 8
#define BK 64
#define BM 128
#define KC (NODES / SK)
#define NIT (KC / BK)

typedef __attribute__((ext_vector_type(8))) short          bf16x8;
typedef __attribute__((ext_vector_type(4))) float          f32x4;
typedef __attribute__((ext_vector_type(4))) unsigned short u16x4;
typedef __attribute__((ext_vector_type(8))) unsigned short u16x8;

#define GLD16(g, l) __builtin_amdgcn_global_load_lds( \
    (const __attribute__((address_space(1))) void*)(g), \
    (__attribute__((address_space(3))) void*)(l), 16, 0, 0)
#define GLD4(g, l) __builtin_amdgcn_global_load_lds( \
    (const __attribute__((address_space(1))) void*)(g), \
    (__attribute__((address_space(3))) void*)(l), 4, 0, 0)

__device__ __forceinline__ unsigned short f2b(float f) {
  union { float f; uint32_t u; } v; v.f = f;
  return (unsigned short)((v.u + 0x7FFFu + ((v.u >> 16) & 1u)) >> 16);
}
__device__ __forceinline__ float b2f(unsigned short h) {
  union { uint32_t u; float f; } v; v.u = ((uint32_t)h) << 16;
  return v.f;
}

// ---------------------------------------------------------------------------
// adj [k][i] fp32 -> maskTb [i][k/8] bit-packed. [R12's strip pack, best]
// ---------------------------------------------------------------------------
__global__ __launch_bounds__(256) void k_pack(const float* __restrict__ adj,
                                              uint8_t* __restrict__ maskTb) {
  const int tid = threadIdx.x;
  const int ic = (tid & 15) * 4;
  const int tb = tid >> 4;
  const int i0 = blockIdx.x * 64;
  const int k0 = blockIdx.y * 512;
  uint32_t acc[4] = {0u, 0u, 0u, 0u};
  const float* base = adj + (size_t)(k0 + tb * 32) * NODES + i0 + ic;
  #pragma unroll
  for (int rg = 0; rg < 4; ++rg) {
    #pragma unroll
    for (int j = 0; j < 8; ++j) {
      const float4 f = *reinterpret_cast<const float4*>(base + (size_t)(rg * 8 + j) * NODES);
      const uint32_t bit = 1u << (rg * 8 + j);
      if (f.x > 0.f) acc[0] |= bit;
      if (f.y > 0.f) acc[1] |= bit;
      if (f.z > 0.f) acc[2] |= bit;
      if (f.w > 0.f) acc[3] |= bit;
    }
  }
  #pragma unroll
  for (int j = 0; j < 4; ++j)
    *reinterpret_cast<uint32_t*>(
        &maskTb[(size_t)(i0 + ic + j) * (NODES / 8) + (k0 >> 3) + tb * 4]) = acc[j];
}

// ---------------------------------------------------------------------------
// deg[i] = popcount(maskTb row i). One wave per node, no atomics, exact.
// ---------------------------------------------------------------------------
__global__ __launch_bounds__(256) void k_deg(const uint8_t* __restrict__ maskTb,
                                             float* __restrict__ deg) {
  const int wv = threadIdx.x >> 6;
  const int lane = threadIdx.x & 63;
  const int i = blockIdx.x * 4 + wv;
  const uint64_t* row = reinterpret_cast<const uint64_t*>(maskTb + (size_t)i * (NODES / 8));
  int cnt = __builtin_popcountll(row[lane]) + __builtin_popcountll(row[64 + lane]);
  #pragma unroll
  for (int o = 32; o > 0; o >>= 1) cnt += __shfl_xor(cnt, o);
  if (lane == 0) deg[i] = (float)cnt;
}

// ---------------------------------------------------------------------------
// UT[l][k][d] = U_layers[l][d][k]
// ---------------------------------------------------------------------------
__global__ __launch_bounds__(256) void k_ut(const float* __restrict__ U,
                                            float* __restrict__ UT) {
  const int l = blockIdx.x;
  const float* Ul = U + (size_t)l * DIM * DIM;
  float* UTl = UT + (size_t)l * DIM * DIM;
  for (int idx = threadIdx.x; idx < DIM * DIM; idx += 256) {
    const int k = idx >> 7, d = idx & 127;
    UTl[idx] = Ul[d * DIM + k];
  }
}

// ---------------------------------------------------------------------------
// hT[d][i] = bf16( (x @ U0 + b0)[i][d] ), 4 nodes per block
// ---------------------------------------------------------------------------
__global__ __launch_bounds__(128) void k_proj(const float* __restrict__ x,
                                              const float* __restrict__ U0,
                                              const float* __restrict__ b0,
                                              unsigned short* __restrict__ hT) {
  __shared__ float xs[4][DIM];
  const int i0 = blockIdx.x * 4;
  const int d = threadIdx.x;
  #pragma unroll
  for (int q = 0; q < 4; ++q) xs[q][d] = x[(size_t)(i0 + q) * DIM + d];
  __syncthreads();
  const float b = b0[d];
  float a0 = b, a1 = b, a2 = b, a3 = b;
  #pragma unroll 4
  for (int k = 0; k < DIM; ++k) {
    const float u = U0[k * DIM + d];
    a0 += xs[0][k] * u; a1 += xs[1][k] * u;
    a2 += xs[2][k] * u; a3 += xs[3][k] * u;
  }
  u16x4 v; v.x = f2b(a0); v.y = f2b(a1); v.z = f2b(a2); v.w = f2b(a3);
  *reinterpret_cast<u16x4*>(&hT[(size_t)d * NODES + i0]) = v;
}

// ---------------------------------------------------------------------------
// partials[sk][i][d] (bf16) = sum_{k in chunk} bit(maskTb[i][k]) * hT[d][k]
// 128x128 tile, BK=64, 4 waves. A: raw bits in 3 KB triple-buffered LDS
// (async GLD4); expand ONE ITERATION AHEAD into REGISTER fragments
// A0/A1[4][2] (64 cndmask under the MFMA shadow - R12's schedule, register
// destination). Deletes the 36 KB As buffer and 12 b128 LDS ops/thread/iter.
// B: hT via global_load_lds + XOR swizzle, dbuf. ONE barrier per iter.
// Epilogue stores bf16 partials.
// ---------------------------------------------------------------------------
__global__ __launch_bounds__(256, 2) void k_gemm(const uint8_t* __restrict__ maskTb,
                                                 const unsigned short* __restrict__ hT,
                                                 unsigned short* __restrict__ partials) {
  __shared__ __attribute__((aligned(16))) char Bs[2][128 * BK * 2];   // 32 KB
  __shared__ __attribute__((aligned(16))) uint8_t Ab[3][128 * 8];     // 3 KB
  const int tid = threadIdx.x;
  const int lane = tid & 63;
  const int wv = tid >> 6;
  const int wm = wv >> 1, wn = wv & 1;
  const int m0 = blockIdx.x * BM;
  const int sk = blockIdx.y;
  const size_t kbase = (size_t)sk * KC;

  // A-bits staging source: thread covers (row = tid>>1, half = tid&1)
  const char* gA = (const char*)(maskTb
      + (size_t)(m0 + (tid >> 1)) * (NODES / 8) + (kbase >> 3) + (tid & 1) * 4);

  // B staging sources: 4 x 16B/thread x 256 threads = 16384 B (full Bs tile)
  const char* gB[4];
  #pragma unroll
  for (int rr = 0; rr < 4; ++rr) {
    const int F = rr * 4096 + tid * 16;
    const int row = F >> 7;
    const int s = ((F >> 4) & 7) ^ (row & 7);
    gB[rr] = (const char*)(hT + ((size_t)row * NODES + kbase + s * 8));
  }

  f32x4 acc[4][4];
  #pragma unroll
  for (int a = 0; a < 4; ++a)
    #pragma unroll
    for (int b = 0; b < 4; ++b) acc[a][b] = (f32x4){0.f, 0.f, 0.f, 0.f};

  auto STAGE_B = [&](int b) {
    #pragma unroll
    for (int rr = 0; rr < 4; ++rr) {
      GLD16(gB[rr], (char*)Bs[b] + rr * 4096 + tid * 16);
      gB[rr] += BK * 2;
    }
  };
  auto STAGE_A = [&](int b) {
    GLD4(gA, (char*)Ab[b] + tid * 4);
    gA += 8;
  };

  const int hi = lane >> 4;              // 0..3
  const int rr_ = lane & 15;
  bf16x8 A0[4][2], A1[4][2];

  auto EXPAND_REG = [&](int b, bf16x8 (&arr)[4][2]) {
    #pragma unroll
    for (int m4 = 0; m4 < 4; ++m4) {
      const uint64_t w = *reinterpret_cast<const uint64_t*>(
          &Ab[b][(wm * 64 + m4 * 16 + rr_) * 8]);
      #pragma unroll
      for (int kk = 0; kk < 2; ++kk) {
        const uint32_t by = (uint32_t)(w >> ((kk * 4 + hi) * 8)) & 0xFFu;
        u16x8 e;
        #pragma unroll
        for (int j = 0; j < 8; ++j) e[j] = ((by >> j) & 1u) ? 0x3F80 : 0;
        arr[m4][kk] = (bf16x8)e;
      }
    }
  };
  auto COMPUTE = [&](int buf, bf16x8 (&arr)[4][2]) {
    #pragma unroll
    for (int kk = 0; kk < 2; ++kk) {
      bf16x8 bv[4];
      #pragma unroll
      for (int n4 = 0; n4 < 4; ++n4) {
        const int row = wn * 64 + n4 * 16 + rr_;
        const int s = (kk * 4 + hi) ^ (row & 7);
        bv[n4] = *reinterpret_cast<const bf16x8*>(&Bs[buf][row * 128 + s * 16]);
      }
      __builtin_amdgcn_s_setprio(1);
      #pragma unroll
      for (int m4 = 0; m4 < 4; ++m4)
        #pragma unroll
        for (int n4 = 0; n4 < 4; ++n4)
          acc[m4][n4] = __builtin_amdgcn_mfma_f32_16x16x32_bf16(
              arr[m4][kk], bv[n4], acc[m4][n4], 0, 0, 0);
      __builtin_amdgcn_s_setprio(0);
    }
  };

  // prologue: bits for tiles 0,1 + B tile 0 in flight
  STAGE_A(0);
  STAGE_A(1);
  STAGE_B(0);
  __syncthreads();            // all staging landed
  EXPAND_REG(0, A0);          // fragments for tile 0

  #pragma unroll 1
  for (int t2 = 0; t2 < NIT / 2; ++t2) {
    const int te = 2 * t2, to = te + 1;
    // even iter: compute tile te from Bs[0]/A0; prep tile te+1 (A1) + stage te+2
    STAGE_B(1);
    if (te + 2 < NIT) STAGE_A((te + 2) % 3);
    EXPAND_REG((to) % 3, A1);          // Ab[to] published at prev barrier
    COMPUTE(0, A0);
    __syncthreads();
    // odd iter: compute tile to from Bs[1]/A1; prep tile to+1 (A0) + stage to+2
    if (to + 1 < NIT) {
      STAGE_B(0);
      if (to + 2 < NIT) STAGE_A((to + 2) % 3);
      EXPAND_REG((to + 1) % 3, A0);
    }
    COMPUTE(1, A1);
    __syncthreads();
  }

  unsigned short* outp = partials + (size_t)sk * NODES * DIM;
  #pragma unroll
  for (int m4 = 0; m4 < 4; ++m4) {
    #pragma unroll
    for (int n4 = 0; n4 < 4; ++n4) {
      const int col = wn * 64 + n4 * 16 + rr_;
      #pragma unroll
      for (int r = 0; r < 4; ++r) {
        const int rowg = m0 + wm * 64 + m4 * 16 + hi * 4 + r;
        outp[(size_t)rowg * DIM + col] = f2b(acc[m4][n4][r]);
      }
    }
  }
}

// ---------------------------------------------------------------------------
// h_next = relu((sum_sk partials / deg) @ UT), 32 nodes per block.
// partials are bf16; summed in fp32.
// ---------------------------------------------------------------------------
template <bool LAST>
__global__ __launch_bounds__(256, 2) void k_layer(const unsigned short* __restrict__ partials,
                                                  const float* __restrict__ deg,
                                                  const float* __restrict__ UTl,
                                                  unsigned short* __restrict__ hT,
                                                  float* __restrict__ out) {
  __shared__ float Us[64 * DIM];   // 32 KB (half of UT at a time)
  __shared__ float a[32 * DIM];    // 16 KB
  const int tid = threadIdx.x;
  const int i0 = blockIdx.x * 32;

  // stage a = (sum_sk partials)/deg  (bf16 loads, fp32 accumulate)
  {
    float4 av[4];
    #pragma unroll
    for (int q = 0; q < 4; ++q) av[q] = make_float4(0.f, 0.f, 0.f, 0.f);
    const size_t base = (size_t)i0 * DIM;
    for (int s = 0; s < SK; ++s) {
      const unsigned short* ps = partials + (size_t)s * NODES * DIM + base;
      #pragma unroll
      for (int q = 0; q < 4; ++q) {
        const u16x4 v = *reinterpret_cast<const u16x4*>(&ps[(tid + q * 256) * 4]);
        av[q].x += b2f(v.x); av[q].y += b2f(v.y);
        av[q].z += b2f(v.z); av[q].w += b2f(v.w);
      }
    }
    float4* a4 = reinterpret_cast<float4*>(a);
    #pragma unroll
    for (int q = 0; q < 4; ++q) {
      const int f4 = tid + q * 256;
      const float dg = deg[i0 + (f4 >> 5)];
      av[q].x /= dg; av[q].y /= dg; av[q].z /= dg; av[q].w /= dg;
      a4[f4] = av[q];
    }
  }

  const int dp = tid & 127;
  const int grp = tid >> 7;
  float z[16];
  #pragma unroll
  for (int q = 0; q < 16; ++q) z[q] = 0.f;

  const float4* src4 = reinterpret_cast<const float4*>(UTl);
  const float4* a4 = reinterpret_cast<const float4*>(a);
  float4* Us4 = reinterpret_cast<float4*>(Us);

  #pragma unroll
  for (int kh = 0; kh < 2; ++kh) {
    __syncthreads();
    #pragma unroll
    for (int q = 0; q < 8; ++q) Us4[tid + q * 256] = src4[kh * 2048 + tid + q * 256];
    __syncthreads();
    #pragma unroll
    for (int nb = 0; nb < 4; ++nb) {
      const int n0 = grp * 16 + nb * 4;
      #pragma unroll 4
      for (int k4 = 0; k4 < 16; ++k4) {
        const float4 q0 = a4[(n0 + 0) * 32 + kh * 16 + k4];
        const float4 q1 = a4[(n0 + 1) * 32 + kh * 16 + k4];
        const float4 q2 = a4[(n0 + 2) * 32 + kh * 16 + k4];
        const float4 q3 = a4[(n0 + 3) * 32 + kh * 16 + k4];
        const float u0 = Us[(k4 * 4 + 0) * DIM + dp];
        const float u1 = Us[(k4 * 4 + 1) * DIM + dp];
        const float u2 = Us[(k4 * 4 + 2) * DIM + dp];
        const float u3 = Us[(k4 * 4 + 3) * DIM + dp];
        z[nb * 4 + 0] += q0.x * u0 + q0.y * u1 + q0.z * u2 + q0.w * u3;
        z[nb * 4 + 1] += q1.x * u0 + q1.y * u1 + q1.z * u2 + q1.w * u3;
        z[nb * 4 + 2] += q2.x * u0 + q2.y * u1 + q2.z * u2 + q2.w * u3;
        z[nb * 4 + 3] += q3.x * u0 + q3.y * u1 + q3.z * u2 + q3.w * u3;
      }
    }
  }

  #pragma unroll
  for (int nb = 0; nb < 4; ++nb) {
    const int n0 = grp * 16 + nb * 4;
    if (LAST) {
      #pragma unroll
      for (int q = 0; q < 4; ++q)
        out[(size_t)(i0 + n0 + q) * DIM + dp] = fmaxf(z[nb * 4 + q], 0.f);
    } else {
      u16x4 v;
      v.x = f2b(fmaxf(z[nb * 4 + 0], 0.f));
      v.y = f2b(fmaxf(z[nb * 4 + 1], 0.f));
      v.z = f2b(fmaxf(z[nb * 4 + 2], 0.f));
      v.w = f2b(fmaxf(z[nb * 4 + 3], 0.f));
      *reinterpret_cast<u16x4*>(&hT[(size_t)dp * NODES + i0 + n0]) = v;
    }
  }
}

// ---------------------------------------------------------------------------
// Fallback (small ws): fp32 naive path, correctness only
// ---------------------------------------------------------------------------
__global__ __launch_bounds__(256) void k_deg_naive(const float* __restrict__ adj,
                                                   float* __restrict__ deg) {
  const int i = blockIdx.x * 256 + threadIdx.x;
  const int r0 = blockIdx.y * 256;
  float p = 0.f;
  for (int r = 0; r < 256; ++r) p += adj[(size_t)(r0 + r) * NODES + i];
  atomicAdd(&deg[i], p);
}

__global__ __launch_bounds__(128) void k_proj_naive(const float* __restrict__ x,
                                                    const float* __restrict__ U0,
                                                    const float* __restrict__ b0,
                                                    float* __restrict__ h) {
  __shared__ float xs[DIM];
  const int i = blockIdx.x;
  const int d = threadIdx.x;
  xs[d] = x[(size_t)i * DIM + d];
  __syncthreads();
  float acc = b0[d];
  for (int k = 0; k < DIM; ++k) acc += xs[k] * U0[k * DIM + d];
  h[(size_t)i * DIM + d] = acc;
}

__global__ __launch_bounds__(128) void k_agg_naive(const float* __restrict__ adj,
                                                   const float* __restrict__ h,
                                                   float* __restrict__ agg) {
  __shared__ float colv[128];
  const int i = blockIdx.x;
  const int d = threadIdx.x;
  float acc = 0.f;
  for (int j0 = 0; j0 < NODES; j0 += 128) {
    __syncthreads();
    colv[d] = adj[(size_t)(j0 + d) * NODES + i];
    __syncthreads();
    for (int jj = 0; jj < 128; ++jj)
      if (colv[jj] > 0.f) acc += h[(size_t)(j0 + jj) * DIM + d];
  }
  agg[(size_t)i * DIM + d] = acc;
}

template <bool LAST>
__global__ __launch_bounds__(128) void k_layer_naive(const float* __restrict__ agg,
                                                     const float* __restrict__ deg,
                                                     const float* __restrict__ Ul,
                                                     float* __restrict__ hout,
                                                     float* __restrict__ out) {
  __shared__ float ar[DIM];
  const int i = blockIdx.x;
  const int d = threadIdx.x;
  ar[d] = agg[(size_t)i * DIM + d] / deg[i];
  __syncthreads();
  float zv = 0.f;
  for (int k = 0; k < DIM; ++k) zv += ar[k] * Ul[d * DIM + k];
  zv = fmaxf(zv, 0.f);
  (LAST ? out : hout)[(size_t)i * DIM + d] = zv;
}

// ---------------------------------------------------------------------------
extern "C" void kernel_launch(void* const* d_in, const int* in_sizes, int n_in,
                              void* d_out, int out_size, void* d_ws, size_t ws_size,
                              hipStream_t stream) {
  const float* x   = (const float*)d_in[0];
  const float* adj = (const float*)d_in[1];
  const float* U0  = (const float*)d_in[2];
  const float* b0  = (const float*)d_in[3];
  const float* UL  = (const float*)d_in[4];
  float* out = (float*)d_out;
  char* ws = (char*)d_ws;

  const size_t maskb_b = (size_t)NODES * (NODES / 8);      // 8 MB
  const size_t parts_b = (size_t)SK * NODES * DIM * 2;     // 16 MB (bf16)
  const size_t hT_b    = (size_t)DIM * NODES * 2;
  const size_t ut_b    = (size_t)NLAYERS * DIM * DIM * 4;
  const size_t deg_b   = (size_t)NODES * 4;
  size_t off = 0;
  const size_t o_mask  = off; off += (maskb_b + 255) & ~(size_t)255;
  const size_t o_parts = off; off += (parts_b + 255) & ~(size_t)255;
  const size_t o_hT    = off; off += (hT_b + 255) & ~(size_t)255;
  const size_t o_ut    = off; off += (ut_b + 255) & ~(size_t)255;
  const size_t o_deg   = off; off += (deg_b + 255) & ~(size_t)255;

  if (ws_size >= off) {
    uint8_t* maskTb = (uint8_t*)(ws + o_mask);
    unsigned short* parts = (unsigned short*)(ws + o_parts);
    unsigned short* hT = (unsigned short*)(ws + o_hT);
    float* UT = (float*)(ws + o_ut);
    float* deg = (float*)(ws + o_deg);

    k_pack<<<dim3(NODES / 64, NODES / 512), 256, 0, stream>>>(adj, maskTb);
    k_deg<<<NODES / 4, 256, 0, stream>>>(maskTb, deg);
    k_ut<<<NLAYERS, 256, 0, stream>>>(UL, UT);
    k_proj<<<NODES / 4, 128, 0, stream>>>(x, U0, b0, hT);
    for (int l = 0; l < NLAYERS; ++l) {
      k_gemm<<<dim3(NODES / BM, SK), 256, 0, stream>>>(maskTb, hT, parts);
      if (l == NLAYERS - 1)
        k_layer<true><<<NODES / 32, 256, 0, stream>>>(parts, deg, UT + l * DIM * DIM, hT, out);
      else
        k_layer<false><<<NODES / 32, 256, 0, stream>>>(parts, deg, UT + l * DIM * DIM, hT, out);
    }
  } else {
    float* h   = (float*)(ws);
    float* agg = (float*)(ws + (size_t)NODES * DIM * 4);
    float* deg = (float*)(ws + (size_t)2 * NODES * DIM * 4);
    hipMemsetAsync(deg, 0, (size_t)NODES * 4, stream);
    k_deg_naive<<<dim3(NODES / 256, NODES / 256), 256, 0, stream>>>(adj, deg);
    k_proj_naive<<<NODES, 128, 0, stream>>>(x, U0, b0, h);
    for (int l = 0; l < NLAYERS; ++l) {
      k_agg_naive<<<NODES, 128, 0, stream>>>(adj, h, agg);
      if (l == NLAYERS - 1)
        k_layer_naive<true><<<NODES, 128, 0, stream>>>(agg, deg, UL + (size_t)l * DIM * DIM, h, out);
      else
        k_layer_naive<false><<<NODES, 128, 0, stream>>>(agg, deg, UL + (size_t)l * DIM * DIM, h, out);
    }
  }
}

// Round 17
// 198.069 us; speedup vs baseline: 1.0772x; 1.0772x over previous
//
#include <hip/hip_runtime.h>
#include <stdint.h>

#define NODES 8192
#define DIM   128
#define NLAYERS 3
#define SK 8
#define BK 64
#define BM 128
#define KC (NODES / SK)
#define NIT (KC / BK)
#define ROWP 72   // padded A-row stride in u16 (144 B, 16B-aligned)

typedef __attribute__((ext_vector_type(8))) short          bf16x8;
typedef __attribute__((ext_vector_type(4))) float          f32x4;
typedef __attribute__((ext_vector_type(4))) unsigned short u16x4;
typedef __attribute__((ext_vector_type(8))) unsigned short u16x8;

#define GLD16(g, l) __builtin_amdgcn_global_load_lds( \
    (const __attribute__((address_space(1))) void*)(g), \
    (__attribute__((address_space(3))) void*)(l), 16, 0, 0)

__device__ __forceinline__ unsigned short f2b(float f) {
  union { float f; uint32_t u; } v; v.f = f;
  return (unsigned short)((v.u + 0x7FFFu + ((v.u >> 16) & 1u)) >> 16);
}
__device__ __forceinline__ float b2f(unsigned short h) {
  union { uint32_t u; float f; } v; v.u = ((uint32_t)h) << 16;
  return v.f;
}

// ---------------------------------------------------------------------------
// adj [k][i] fp32 -> maskTb [i][k/8] bit-packed. [strip pack, best measured]
// ---------------------------------------------------------------------------
__global__ __launch_bounds__(256) void k_pack(const float* __restrict__ adj,
                                              uint8_t* __restrict__ maskTb) {
  const int tid = threadIdx.x;
  const int ic = (tid & 15) * 4;
  const int tb = tid >> 4;
  const int i0 = blockIdx.x * 64;
  const int k0 = blockIdx.y * 512;
  uint32_t acc[4] = {0u, 0u, 0u, 0u};
  const float* base = adj + (size_t)(k0 + tb * 32) * NODES + i0 + ic;
  #pragma unroll
  for (int rg = 0; rg < 4; ++rg) {
    #pragma unroll
    for (int j = 0; j < 8; ++j) {
      const float4 f = *reinterpret_cast<const float4*>(base + (size_t)(rg * 8 + j) * NODES);
      const uint32_t bit = 1u << (rg * 8 + j);
      if (f.x > 0.f) acc[0] |= bit;
      if (f.y > 0.f) acc[1] |= bit;
      if (f.z > 0.f) acc[2] |= bit;
      if (f.w > 0.f) acc[3] |= bit;
    }
  }
  #pragma unroll
  for (int j = 0; j < 4; ++j)
    *reinterpret_cast<uint32_t*>(
        &maskTb[(size_t)(i0 + ic + j) * (NODES / 8) + (k0 >> 3) + tb * 4]) = acc[j];
}

// ---------------------------------------------------------------------------
// FUSED aux kernel: proj (8 nodes/block) + deg (8 nodes/block) + ut (blocks 0-2)
// grid = NODES/8 = 1024 blocks x 256 threads. Replaces 3 launches with 1.
// ---------------------------------------------------------------------------
__global__ __launch_bounds__(256) void k_aux(const float* __restrict__ x,
                                             const float* __restrict__ U0,
                                             const float* __restrict__ b0,
                                             const uint8_t* __restrict__ maskTb,
                                             const float* __restrict__ UL,
                                             unsigned short* __restrict__ hT,
                                             float* __restrict__ deg,
                                             float* __restrict__ UT) {
  __shared__ float xs[8][DIM];
  const int tid = threadIdx.x;
  const int i0 = blockIdx.x * 8;
  const int d = tid & 127;
  const int half = tid >> 7;       // 0,1 -> nodes i0+half*4 .. +3

  // ---- proj: hT[d][i] = bf16(x @ U0 + b0), 8 nodes ----
  #pragma unroll
  for (int q = 0; q < 4; ++q)
    xs[half * 4 + q][d] = x[(size_t)(i0 + half * 4 + q) * DIM + d];
  __syncthreads();
  {
    const float b = b0[d];
    float a0 = b, a1 = b, a2 = b, a3 = b;
    #pragma unroll 4
    for (int k = 0; k < DIM; ++k) {
      const float u = U0[k * DIM + d];
      a0 += xs[half * 4 + 0][k] * u;
      a1 += xs[half * 4 + 1][k] * u;
      a2 += xs[half * 4 + 2][k] * u;
      a3 += xs[half * 4 + 3][k] * u;
    }
    u16x4 v; v.x = f2b(a0); v.y = f2b(a1); v.z = f2b(a2); v.w = f2b(a3);
    *reinterpret_cast<u16x4*>(&hT[(size_t)d * NODES + i0 + half * 4]) = v;
  }

  // ---- deg: wave wv handles nodes i0+2*wv, i0+2*wv+1 (popcount, exact) ----
  {
    const int wv = tid >> 6;
    const int lane = tid & 63;
    #pragma unroll
    for (int e = 0; e < 2; ++e) {
      const int node = i0 + wv * 2 + e;
      const uint64_t* row = reinterpret_cast<const uint64_t*>(
          maskTb + (size_t)node * (NODES / 8));
      int cnt = __builtin_popcountll(row[lane]) + __builtin_popcountll(row[64 + lane]);
      #pragma unroll
      for (int o = 32; o > 0; o >>= 1) cnt += __shfl_xor(cnt, o);
      if (lane == 0) deg[node] = (float)cnt;
    }
  }

  // ---- ut: blocks 0..2 transpose one U layer each ----
  if (blockIdx.x < NLAYERS) {
    const int l = blockIdx.x;
    const float* Ul = UL + (size_t)l * DIM * DIM;
    float* UTl = UT + (size_t)l * DIM * DIM;
    for (int idx = tid; idx < DIM * DIM; idx += 256) {
      const int k = idx >> 7, dd = idx & 127;
      UTl[idx] = Ul[dd * DIM + k];
    }
  }
}

// ---------------------------------------------------------------------------
// partials[sk][i][d] (bf16) = sum_{k in chunk} bit(maskTb[i][k]) * hT[d][k]
// [= R15's gemm, best measured: LDS As expand-1-ahead, 1 barrier/iter]
// ---------------------------------------------------------------------------
__global__ __launch_bounds__(256, 2) void k_gemm(const uint8_t* __restrict__ maskTb,
                                                 const unsigned short* __restrict__ hT,
                                                 unsigned short* __restrict__ partials) {
  __shared__ __attribute__((aligned(16))) unsigned short As[2][BM * ROWP]; // 2x18 KB
  __shared__ __attribute__((aligned(16))) char Bs[2][128 * BK * 2];        // 2x16 KB
  const int tid = threadIdx.x;
  const int lane = tid & 63;
  const int wv = tid >> 6;
  const int wm = wv >> 1, wn = wv & 1;
  const int m0 = blockIdx.x * BM;
  const int sk = blockIdx.y;
  const size_t kbase = (size_t)sk * KC;

  const int arow = tid >> 1;
  const int ahalf = tid & 1;
  const uint32_t* pbits = reinterpret_cast<const uint32_t*>(
      maskTb + (size_t)(m0 + arow) * (NODES / 8) + (kbase >> 3)) + ahalf;

  const char* gB[4];
  #pragma unroll
  for (int rr = 0; rr < 4; ++rr) {
    const int F = rr * 4096 + tid * 16;
    const int row = F >> 7;
    const int s = ((F >> 4) & 7) ^ (row & 7);
    gB[rr] = (const char*)(hT + ((size_t)row * NODES + kbase + s * 8));
  }

  f32x4 acc[4][4];
  #pragma unroll
  for (int a = 0; a < 4; ++a)
    #pragma unroll
    for (int b = 0; b < 4; ++b) acc[a][b] = (f32x4){0.f, 0.f, 0.f, 0.f};

  auto STAGE_B = [&](int b) {
    #pragma unroll
    for (int rr = 0; rr < 4; ++rr) {
      GLD16(gB[rr], (char*)Bs[b] + rr * 4096 + tid * 16);
      gB[rr] += BK * 2;
    }
  };
  auto EXPAND_A = [&](int b, uint32_t bits) {
    #pragma unroll
    for (int q = 0; q < 4; ++q) {
      u16x8 e;
      #pragma unroll
      for (int j = 0; j < 8; ++j)
        e[j] = ((bits >> (q * 8 + j)) & 1u) ? 0x3F80 : 0;
      *reinterpret_cast<u16x8*>(&As[b][arow * ROWP + ahalf * 32 + q * 8]) = e;
    }
  };
  auto COMPUTE = [&](int cur) {
    #pragma unroll
    for (int kk = 0; kk < 2; ++kk) {
      bf16x8 av[4], bv[4];
      #pragma unroll
      for (int m4 = 0; m4 < 4; ++m4) {
        const int row = wm * 64 + m4 * 16 + (lane & 15);
        av[m4] = *reinterpret_cast<const bf16x8*>(
            &As[cur][row * ROWP + kk * 32 + (lane >> 4) * 8]);
      }
      #pragma unroll
      for (int n4 = 0; n4 < 4; ++n4) {
        const int row = wn * 64 + n4 * 16 + (lane & 15);
        const int s = (kk * 4 + (lane >> 4)) ^ (row & 7);
        bv[n4] = *reinterpret_cast<const bf16x8*>(&Bs[cur][row * 128 + s * 16]);
      }
      __builtin_amdgcn_s_setprio(1);
      #pragma unroll
      for (int m4 = 0; m4 < 4; ++m4)
        #pragma unroll
        for (int n4 = 0; n4 < 4; ++n4)
          acc[m4][n4] = __builtin_amdgcn_mfma_f32_16x16x32_bf16(
              av[m4], bv[n4], acc[m4][n4], 0, 0, 0);
      __builtin_amdgcn_s_setprio(0);
    }
  };

  uint32_t bcur = *pbits; pbits += 2;
  STAGE_B(0);
  EXPAND_A(0, bcur);
  uint32_t bnext = *pbits; pbits += 2;
  __syncthreads();

  #pragma unroll 1
  for (int t = 0; t < NIT; ++t) {
    const int cur = t & 1;
    if (t + 1 < NIT) {
      STAGE_B(cur ^ 1);
      EXPAND_A(cur ^ 1, bnext);
      if (t + 2 < NIT) { bnext = *pbits; pbits += 2; }
    }
    COMPUTE(cur);
    __syncthreads();
  }

  unsigned short* outp = partials + (size_t)sk * NODES * DIM;
  #pragma unroll
  for (int m4 = 0; m4 < 4; ++m4) {
    #pragma unroll
    for (int n4 = 0; n4 < 4; ++n4) {
      const int col = wn * 64 + n4 * 16 + (lane & 15);
      #pragma unroll
      for (int r = 0; r < 4; ++r) {
        const int rowg = m0 + wm * 64 + m4 * 16 + (lane >> 4) * 4 + r;
        outp[(size_t)rowg * DIM + col] = f2b(acc[m4][n4][r]);
      }
    }
  }
}

// ---------------------------------------------------------------------------
// h_next = relu((sum_sk partials / deg) @ UT), 32 nodes per block.
// partials are bf16; summed in fp32.
// ---------------------------------------------------------------------------
template <bool LAST>
__global__ __launch_bounds__(256, 2) void k_layer(const unsigned short* __restrict__ partials,
                                                  const float* __restrict__ deg,
                                                  const float* __restrict__ UTl,
                                                  unsigned short* __restrict__ hT,
                                                  float* __restrict__ out) {
  __shared__ float Us[64 * DIM];
  __shared__ float a[32 * DIM];
  const int tid = threadIdx.x;
  const int i0 = blockIdx.x * 32;

  {
    float4 av[4];
    #pragma unroll
    for (int q = 0; q < 4; ++q) av[q] = make_float4(0.f, 0.f, 0.f, 0.f);
    const size_t base = (size_t)i0 * DIM;
    for (int s = 0; s < SK; ++s) {
      const unsigned short* ps = partials + (size_t)s * NODES * DIM + base;
      #pragma unroll
      for (int q = 0; q < 4; ++q) {
        const u16x4 v = *reinterpret_cast<const u16x4*>(&ps[(tid + q * 256) * 4]);
        av[q].x += b2f(v.x); av[q].y += b2f(v.y);
        av[q].z += b2f(v.z); av[q].w += b2f(v.w);
      }
    }
    float4* a4 = reinterpret_cast<float4*>(a);
    #pragma unroll
    for (int q = 0; q < 4; ++q) {
      const int f4 = tid + q * 256;
      const float dg = deg[i0 + (f4 >> 5)];
      av[q].x /= dg; av[q].y /= dg; av[q].z /= dg; av[q].w /= dg;
      a4[f4] = av[q];
    }
  }

  const int dp = tid & 127;
  const int grp = tid >> 7;
  float z[16];
  #pragma unroll
  for (int q = 0; q < 16; ++q) z[q] = 0.f;

  const float4* src4 = reinterpret_cast<const float4*>(UTl);
  const float4* a4 = reinterpret_cast<const float4*>(a);
  float4* Us4 = reinterpret_cast<float4*>(Us);

  #pragma unroll
  for (int kh = 0; kh < 2; ++kh) {
    __syncthreads();
    #pragma unroll
    for (int q = 0; q < 8; ++q) Us4[tid + q * 256] = src4[kh * 2048 + tid + q * 256];
    __syncthreads();
    #pragma unroll
    for (int nb = 0; nb < 4; ++nb) {
      const int n0 = grp * 16 + nb * 4;
      #pragma unroll 4
      for (int k4 = 0; k4 < 16; ++k4) {
        const float4 q0 = a4[(n0 + 0) * 32 + kh * 16 + k4];
        const float4 q1 = a4[(n0 + 1) * 32 + kh * 16 + k4];
        const float4 q2 = a4[(n0 + 2) * 32 + kh * 16 + k4];
        const float4 q3 = a4[(n0 + 3) * 32 + kh * 16 + k4];
        const float u0 = Us[(k4 * 4 + 0) * DIM + dp];
        const float u1 = Us[(k4 * 4 + 1) * DIM + dp];
        const float u2 = Us[(k4 * 4 + 2) * DIM + dp];
        const float u3 = Us[(k4 * 4 + 3) * DIM + dp];
        z[nb * 4 + 0] += q0.x * u0 + q0.y * u1 + q0.z * u2 + q0.w * u3;
        z[nb * 4 + 1] += q1.x * u0 + q1.y * u1 + q1.z * u2 + q1.w * u3;
        z[nb * 4 + 2] += q2.x * u0 + q2.y * u1 + q2.z * u2 + q2.w * u3;
        z[nb * 4 + 3] += q3.x * u0 + q3.y * u1 + q3.z * u2 + q3.w * u3;
      }
    }
  }

  #pragma unroll
  for (int nb = 0; nb < 4; ++nb) {
    const int n0 = grp * 16 + nb * 4;
    if (LAST) {
      #pragma unroll
      for (int q = 0; q < 4; ++q)
        out[(size_t)(i0 + n0 + q) * DIM + dp] = fmaxf(z[nb * 4 + q], 0.f);
    } else {
      u16x4 v;
      v.x = f2b(fmaxf(z[nb * 4 + 0], 0.f));
      v.y = f2b(fmaxf(z[nb * 4 + 1], 0.f));
      v.z = f2b(fmaxf(z[nb * 4 + 2], 0.f));
      v.w = f2b(fmaxf(z[nb * 4 + 3], 0.f));
      *reinterpret_cast<u16x4*>(&hT[(size_t)dp * NODES + i0 + n0]) = v;
    }
  }
}

// ---------------------------------------------------------------------------
// Fallback (small ws): fp32 naive path, correctness only
// ---------------------------------------------------------------------------
__global__ __launch_bounds__(256) void k_deg_naive(const float* __restrict__ adj,
                                                   float* __restrict__ deg) {
  const int i = blockIdx.x * 256 + threadIdx.x;
  const int r0 = blockIdx.y * 256;
  float p = 0.f;
  for (int r = 0; r < 256; ++r) p += adj[(size_t)(r0 + r) * NODES + i];
  atomicAdd(&deg[i], p);
}

__global__ __launch_bounds__(128) void k_proj_naive(const float* __restrict__ x,
                                                    const float* __restrict__ U0,
                                                    const float* __restrict__ b0,
                                                    float* __restrict__ h) {
  __shared__ float xs[DIM];
  const int i = blockIdx.x;
  const int d = threadIdx.x;
  xs[d] = x[(size_t)i * DIM + d];
  __syncthreads();
  float acc = b0[d];
  for (int k = 0; k < DIM; ++k) acc += xs[k] * U0[k * DIM + d];
  h[(size_t)i * DIM + d] = acc;
}

__global__ __launch_bounds__(128) void k_agg_naive(const float* __restrict__ adj,
                                                   const float* __restrict__ h,
                                                   float* __restrict__ agg) {
  __shared__ float colv[128];
  const int i = blockIdx.x;
  const int d = threadIdx.x;
  float acc = 0.f;
  for (int j0 = 0; j0 < NODES; j0 += 128) {
    __syncthreads();
    colv[d] = adj[(size_t)(j0 + d) * NODES + i];
    __syncthreads();
    for (int jj = 0; jj < 128; ++jj)
      if (colv[jj] > 0.f) acc += h[(size_t)(j0 + jj) * DIM + d];
  }
  agg[(size_t)i * DIM + d] = acc;
}

template <bool LAST>
__global__ __launch_bounds__(128) void k_layer_naive(const float* __restrict__ agg,
                                                     const float* __restrict__ deg,
                                                     const float* __restrict__ Ul,
                                                     float* __restrict__ hout,
                                                     float* __restrict__ out) {
  __shared__ float ar[DIM];
  const int i = blockIdx.x;
  const int d = threadIdx.x;
  ar[d] = agg[(size_t)i * DIM + d] / deg[i];
  __syncthreads();
  float zv = 0.f;
  for (int k = 0; k < DIM; ++k) zv += ar[k] * Ul[d * DIM + k];
  zv = fmaxf(zv, 0.f);
  (LAST ? out : hout)[(size_t)i * DIM + d] = zv;
}

// ---------------------------------------------------------------------------
extern "C" void kernel_launch(void* const* d_in, const int* in_sizes, int n_in,
                              void* d_out, int out_size, void* d_ws, size_t ws_size,
                              hipStream_t stream) {
  const float* x   = (const float*)d_in[0];
  const float* adj = (const float*)d_in[1];
  const float* U0  = (const float*)d_in[2];
  const float* b0  = (const float*)d_in[3];
  const float* UL  = (const float*)d_in[4];
  float* out = (float*)d_out;
  char* ws = (char*)d_ws;

  const size_t maskb_b = (size_t)NODES * (NODES / 8);      // 8 MB
  const size_t parts_b = (size_t)SK * NODES * DIM * 2;     // 16 MB (bf16)
  const size_t hT_b    = (size_t)DIM * NODES * 2;
  const size_t ut_b    = (size_t)NLAYERS * DIM * DIM * 4;
  const size_t deg_b   = (size_t)NODES * 4;
  size_t off = 0;
  const size_t o_mask  = off; off += (maskb_b + 255) & ~(size_t)255;
  const size_t o_parts = off; off += (parts_b + 255) & ~(size_t)255;
  const size_t o_hT    = off; off += (hT_b + 255) & ~(size_t)255;
  const size_t o_ut    = off; off += (ut_b + 255) & ~(size_t)255;
  const size_t o_deg   = off; off += (deg_b + 255) & ~(size_t)255;

  if (ws_size >= off) {
    uint8_t* maskTb = (uint8_t*)(ws + o_mask);
    unsigned short* parts = (unsigned short*)(ws + o_parts);
    unsigned short* hT = (unsigned short*)(ws + o_hT);
    float* UT = (float*)(ws + o_ut);
    float* deg = (float*)(ws + o_deg);

    k_pack<<<dim3(NODES / 64, NODES / 512), 256, 0, stream>>>(adj, maskTb);
    k_aux<<<NODES / 8, 256, 0, stream>>>(x, U0, b0, maskTb, UL, hT, deg, UT);
    for (int l = 0; l < NLAYERS; ++l) {
      k_gemm<<<dim3(NODES / BM, SK), 256, 0, stream>>>(maskTb, hT, parts);
      if (l == NLAYERS - 1)
        k_layer<true><<<NODES / 32, 256, 0, stream>>>(parts, deg, UT + l * DIM * DIM, hT, out);
      else
        k_layer<false><<<NODES / 32, 256, 0, stream>>>(parts, deg, UT + l * DIM * DIM, hT, out);
    }
  } else {
    float* h   = (float*)(ws);
    float* agg = (float*)(ws + (size_t)NODES * DIM * 4);
    float* deg = (float*)(ws + (size_t)2 * NODES * DIM * 4);
    hipMemsetAsync(deg, 0, (size_t)NODES * 4, stream);
    k_deg_naive<<<dim3(NODES / 256, NODES / 256), 256, 0, stream>>>(adj, deg);
    k_proj_naive<<<NODES, 128, 0, stream>>>(x, U0, b0, h);
    for (int l = 0; l < NLAYERS; ++l) {
      k_agg_naive<<<NODES, 128, 0, stream>>>(adj, h, agg);
      if (l == NLAYERS - 1)
        k_layer_naive<true><<<NODES, 128, 0, stream>>>(agg, deg, UL + (size_t)l * DIM * DIM, h, out);
      else
        k_layer_naive<false><<<NODES, 128, 0, stream>>>(agg, deg, UL + (size_t)l * DIM * DIM, h, out);
    }
  }
}